// Round 9
// baseline (691.122 us; speedup 1.0000x reference)
//
#include <hip/hip_runtime.h>
#include <math.h>

// GAT forward. R9:
//  (a) edge kernel: unsigned 32-bit gather offsets (saddr-form loads),
//      full-quad main loop + masked tail (no per-iter cndmask in common path),
//      packed-fp16 merge tail (12 shfls vs 20, pk_fma rescale).
//  (b) fast gelu (exp-based tanh, ~10 ops vs ~25 for tanhf).
//  (c) fc2 fused into fc1 GEMM epilogue (drop k_fc2 + 51MB of traffic).
// Structure: CSR build -> W pack (fp16 frag-major) -> fc0 (fp32) ->
//   2x [ gemm_mfma(k,q,v->fp16; ws->fp32) -> fused edge ] -> fc1+fc2 fused.

typedef _Float16 f16x8 __attribute__((ext_vector_type(8)));
typedef _Float16 h2 __attribute__((ext_vector_type(2)));
typedef float f32x4 __attribute__((ext_vector_type(4)));

__device__ __forceinline__ ushort f2h(float x) {
    union { _Float16 h; ushort u; } v;
    v.h = (_Float16)x;
    return v.u;
}
__device__ __forceinline__ float h2f(ushort u) {
    union { ushort u; _Float16 h; } v;
    v.u = u;
    return (float)v.h;
}

// gelu tanh-approx; tanh(y) via e^{2y}: gelu = x * t / (t + 1), t = exp(2y)
__device__ __forceinline__ float gelu_f(float x) {
    float y = 0.7978845608028654f * (x + 0.044715f * x * x * x);
    float t = __expf(2.f * y);
    return x * t / (t + 1.f);
}

__device__ __forceinline__ h2 pk2(float a, float b) {
    return __builtin_bit_cast(h2, __builtin_amdgcn_cvt_pkrtz(a, b));
}

// ---------------- CSR build ----------------
__global__ void k_zero(int* __restrict__ p, int n) {
    int i = blockIdx.x * blockDim.x + threadIdx.x;
    if (i < n) p[i] = 0;
}

// histogram + per-edge rank (old value of the counter)
__global__ void k_hist(const int* __restrict__ dst, int* __restrict__ deg,
                       int* __restrict__ rank, int e) {
    int i = blockIdx.x * blockDim.x + threadIdx.x;
    if (i < e) rank[i] = atomicAdd(&deg[dst[i]], 1);
}

__global__ __launch_bounds__(256) void k_part(const int* __restrict__ deg,
                                              int* __restrict__ pre,
                                              int* __restrict__ bsum, int n) {
    __shared__ int lds[256];
    int t = threadIdx.x;
    int base = blockIdx.x * 1024 + t * 4;
    int d0 = 0, d1 = 0, d2 = 0, d3 = 0;
    if (base + 3 < n) {
        int4 d = *(const int4*)&deg[base];
        d0 = d.x; d1 = d.y; d2 = d.z; d3 = d.w;
    } else {
        if (base + 0 < n) d0 = deg[base + 0];
        if (base + 1 < n) d1 = deg[base + 1];
        if (base + 2 < n) d2 = deg[base + 2];
        if (base + 3 < n) d3 = deg[base + 3];
    }
    int s0 = d0, s1 = s0 + d1, s2 = s1 + d2, s3 = s2 + d3;
    lds[t] = s3;
    __syncthreads();
    for (int off = 1; off < 256; off <<= 1) {
        int v = (t >= off) ? lds[t - off] : 0;
        __syncthreads();
        lds[t] += v;
        __syncthreads();
    }
    int excl = lds[t] - s3;
    if (base + 0 < n) pre[base + 0] = excl;
    if (base + 1 < n) pre[base + 1] = excl + s0;
    if (base + 2 < n) pre[base + 2] = excl + s1;
    if (base + 3 < n) pre[base + 3] = excl + s2;
    if (t == 255) bsum[blockIdx.x] = lds[255];
}

__global__ void k_scanb(int* __restrict__ bsum, int nb) {
    __shared__ int lds[128];
    int t = threadIdx.x;
    int v = (t < nb) ? bsum[t] : 0;
    lds[t] = v;
    __syncthreads();
    for (int off = 1; off < 128; off <<= 1) {
        int u = (t >= off) ? lds[t - off] : 0;
        __syncthreads();
        lds[t] += u;
        __syncthreads();
    }
    if (t < nb) bsum[t] = lds[t] - v;
}

__global__ __launch_bounds__(256) void k_add(int* __restrict__ rowp,
                                             const int* __restrict__ bsum, int n,
                                             int e) {
    int t = threadIdx.x;
    int base = blockIdx.x * 1024 + t * 4;
    int off = bsum[blockIdx.x];
#pragma unroll
    for (int j = 0; j < 4; ++j) {
        int i = base + j;
        if (i < n) rowp[i] += off;
    }
    if (blockIdx.x == 0 && t == 0) rowp[n] = e;
}

// atomic-free scatter: position = rowp[dst] + rank
__global__ void k_scatter(const int* __restrict__ src, const int* __restrict__ dst,
                          const int* __restrict__ rank, const int* __restrict__ rowp,
                          int* __restrict__ csrc, int e) {
    int i = blockIdx.x * blockDim.x + threadIdx.x;
    if (i < e) csrc[rowp[dst[i]] + rank[i]] = src[i];
}

// ---------------- W pack: fp32 [128][128] -> fp16 frag-major ----------------
__global__ void k_pack(const float* __restrict__ Wk, const float* __restrict__ Wq,
                       const float* __restrict__ Wv, const float* __restrict__ Ws,
                       const float* __restrict__ Wfc1, ushort* __restrict__ Wp) {
    int id = blockIdx.y;
    const float* src;
    if (id < 8) {
        int m = id & 3, layer = id >> 2;
        src = (m == 0) ? Wk : (m == 1) ? Wq : (m == 2) ? Wv : Ws;
        src += layer * 16384;
    } else {
        src = Wfc1;
    }
    int o = blockIdx.x * 256 + threadIdx.x;
    int j = o & 7, l = (o >> 3) & 63, nf = (o >> 9) & 7, kc = o >> 12;
    int row = kc * 32 + ((l >> 4) << 3) + j;
    int col = nf * 16 + (l & 15);
    Wp[id * 16384 + o] = f2h(src[row * 128 + col]);
}

// ---------------- fc0: [N,16] @ [16,128] + b (fp32) ----------------
__global__ __launch_bounds__(256) void k_fc0(const float* __restrict__ X,
                                             const float* __restrict__ W,
                                             const float* __restrict__ b,
                                             float* __restrict__ H, int n) {
    __shared__ float Ws[16 * 128];
    __shared__ float xs[2][16];
    int t = threadIdx.x;
#pragma unroll
    for (int i = 0; i < 8; ++i) Ws[t + i * 256] = W[t + i * 256];
    if (t < 32) {
        int nn = blockIdx.x * 2 + (t >> 4);
        xs[t >> 4][t & 15] = (nn < n) ? X[nn * 16 + (t & 15)] : 0.f;
    }
    __syncthreads();
    int nd = blockIdx.x * 2 + (t >> 7);
    if (nd < n) {
        int c = t & 127;
        float acc = b[c];
#pragma unroll
        for (int j = 0; j < 16; ++j) acc += xs[t >> 7][j] * Ws[j * 128 + c];
        H[nd * 128 + c] = acc;
    }
}

// ---------------- MFMA GEMM: [N,128] @ [128,128] x nmat ----------------
// flags: bit m = fp16 out; bit 8+m = gelu; bit 16 = fuse fc2 epilogue
// (fc1 path: gelu applied inside fused path; out2 = [n,4] fp32).
__global__ __launch_bounds__(256) void k_gemm_mfma(
    const float* __restrict__ A, int n, const ushort* __restrict__ Wp,
    const float* __restrict__ b0, void* __restrict__ o0,
    const float* __restrict__ b1, void* __restrict__ o1,
    const float* __restrict__ b2_, void* __restrict__ o2,
    const float* __restrict__ b3, void* __restrict__ o3,
    const float* __restrict__ W2, const float* __restrict__ bias2,
    float* __restrict__ out2, int flags, int nmat) {
    __shared__ ushort As[64 * 128];  // 16 KB
    char* Asb = (char*)As;
    int t = threadIdx.x;
    int rbase = blockIdx.x * 64;

#pragma unroll
    for (int i = 0; i < 8; ++i) {
        int f = t * 4 + i * 1024;
        int r = f >> 7, c = f & 127;
        float4 v = {0.f, 0.f, 0.f, 0.f};
        if (rbase + r < n) v = *(const float4*)&A[(size_t)(rbase + r) * 128 + c];
        ushort4 u;
        u.x = f2h(v.x); u.y = f2h(v.y); u.z = f2h(v.z); u.w = f2h(v.w);
        int byte = (r * 256 + c * 2) ^ ((r & 7) << 4);
        *(ushort4*)(Asb + byte) = u;
    }
    __syncthreads();

    int w = t >> 6, l = t & 63;
    int arow = w * 16 + (l & 15);
    int kq = l >> 4;

    f16x8 a[4];
#pragma unroll
    for (int kc = 0; kc < 4; ++kc) {
        int byte = (arow * 256 + kc * 64 + kq * 16) ^ ((arow & 7) << 4);
        a[kc] = *(const f16x8*)(Asb + byte);
    }

    int fuse = (flags >> 16) & 1;

    for (int m = 0; m < nmat; ++m) {
        const float* bias; void* op;
        if (m == 0)      { bias = b0; op = o0; }
        else if (m == 1) { bias = b1; op = o1; }
        else if (m == 2) { bias = b2_; op = o2; }
        else             { bias = b3; op = o3; }
        int isf16 = (flags >> m) & 1;
        int act   = (flags >> (8 + m)) & 1;
        const ushort* wb = Wp + m * 16384;

        f32x4 acc[8];
#pragma unroll
        for (int nf = 0; nf < 8; ++nf) acc[nf] = (f32x4){0.f, 0.f, 0.f, 0.f};

#pragma unroll
        for (int kc = 0; kc < 4; ++kc) {
#pragma unroll
            for (int nf = 0; nf < 8; ++nf) {
                f16x8 b = *(const f16x8*)(wb + (((kc * 8 + nf) * 64 + l) << 3));
                acc[nf] = __builtin_amdgcn_mfma_f32_16x16x32_f16(a[kc], b, acc[nf], 0, 0, 0);
            }
        }

        if (fuse) {
            // fc1 gelu + fc2 [128x4] fused: per-lane partials, 16-lane reduce
            float pj[4][4];
#pragma unroll
            for (int r = 0; r < 4; ++r)
#pragma unroll
                for (int j = 0; j < 4; ++j) pj[r][j] = 0.f;
#pragma unroll
            for (int nf = 0; nf < 8; ++nf) {
                int col = nf * 16 + (l & 15);
                float4 w2v = *(const float4*)&W2[col * 4];
                float bia = bias[col];
#pragma unroll
                for (int r = 0; r < 4; ++r) {
                    float o = gelu_f(acc[nf][r] + bia);
                    pj[r][0] += o * w2v.x;
                    pj[r][1] += o * w2v.y;
                    pj[r][2] += o * w2v.z;
                    pj[r][3] += o * w2v.w;
                }
            }
#pragma unroll
            for (int off = 1; off < 16; off <<= 1)
#pragma unroll
                for (int r = 0; r < 4; ++r)
#pragma unroll
                    for (int j = 0; j < 4; ++j)
                        pj[r][j] += __shfl_xor(pj[r][j], off);
            int jj = l & 15;
            if (jj < 4) {
#pragma unroll
                for (int r = 0; r < 4; ++r) {
                    int row = rbase + w * 16 + (l >> 4) * 4 + r;
                    if (row < n) {
                        float v = (jj == 0) ? pj[r][0] : (jj == 1) ? pj[r][1]
                                : (jj == 2) ? pj[r][2] : pj[r][3];
                        out2[(size_t)row * 4 + jj] = v + bias2[jj];
                    }
                }
            }
        } else {
#pragma unroll
            for (int nf = 0; nf < 8; ++nf) {
                int col = nf * 16 + (l & 15);
                float bia = bias[col];
#pragma unroll
                for (int r = 0; r < 4; ++r) {
                    int row = rbase + w * 16 + (l >> 4) * 4 + r;
                    if (row < n) {
                        float o = acc[nf][r] + bia;
                        if (act) o = gelu_f(o);
                        if (isf16) ((ushort*)op)[(size_t)row * 128 + col] = f2h(o);
                        else       ((float*)op)[(size_t)row * 128 + col] = o;
                    }
                }
            }
        }
    }
}

// ---------------- fused edge phase: one wave/dst node, 4 edges/iter --------
// quarter qb = lane>>4 owns edge slot; (lane&15) holds feats [fb, fb+8).
// QK via fdot2 (fp32 acc), 3-shfl 8-lane head reduce, branchless online
// softmax, PV accumulate packed fp16. Full quads unmasked; one masked tail.
// Quarter states merged in packed fp16 via xor16/xor32.
__global__ void k_edge_hf(const ushort* __restrict__ K, const ushort* __restrict__ Q,
                          const ushort* __restrict__ V, const int* __restrict__ rowp,
                          const int* __restrict__ csrc, float* __restrict__ H, int n,
                          int act) {
    int wid = (int)((blockIdx.x * blockDim.x + threadIdx.x) >> 6);
    int lane = threadIdx.x & 63;
    if (wid >= n) return;
    int qb = lane >> 4;                 // edge slot within quad
    unsigned fb = (lane & 15) * 8u;     // feature base
    int e0 = rowp[wid], e1 = rowp[wid + 1];

    uint4 qr = *(const uint4*)(Q + (((unsigned)wid << 7) + fb));
    h2 q0 = __builtin_bit_cast(h2, qr.x), q1 = __builtin_bit_cast(h2, qr.y);
    h2 q2 = __builtin_bit_cast(h2, qr.z), q3 = __builtin_bit_cast(h2, qr.w);

    float m = -1e30f, denom = 0.f;
    h2 hz = {(_Float16)0.f, (_Float16)0.f};
    h2 acc0 = hz, acc1 = hz, acc2 = hz, acc3 = hz;

    for (int eb = e0; eb < e1; eb += 64) {
        int cnt = min(64, e1 - eb);
        int sl = (eb + lane < e1) ? csrc[eb + lane] : 0;
        int full = cnt >> 2;
#pragma unroll 2
        for (int j = 0; j < full; ++j) {
            int s = __shfl(sl, 4 * j + qb);
            unsigned off = ((unsigned)s << 7) + fb;
            uint4 kr = *(const uint4*)(K + off);
            float sc = __builtin_amdgcn_fdot2(__builtin_bit_cast(h2, kr.x), q0,
                       __builtin_amdgcn_fdot2(__builtin_bit_cast(h2, kr.y), q1,
                       __builtin_amdgcn_fdot2(__builtin_bit_cast(h2, kr.z), q2,
                       __builtin_amdgcn_fdot2(__builtin_bit_cast(h2, kr.w), q3,
                                              0.f, false), false), false), false);
            sc += __shfl_xor(sc, 1);
            sc += __shfl_xor(sc, 2);
            sc += __shfl_xor(sc, 4);    // 8-lane head-group reduce
            uint4 vr = *(const uint4*)(V + off);
            float mn = fmaxf(m, sc);
            float ss = __expf(m - mn);
            float p = __expf(sc - mn);
            denom = denom * ss + p;
            h2 hp = pk2(p, p);
            h2 hs = pk2(ss, ss);
            acc0 = __builtin_bit_cast(h2, vr.x) * hp + acc0 * hs;
            acc1 = __builtin_bit_cast(h2, vr.y) * hp + acc1 * hs;
            acc2 = __builtin_bit_cast(h2, vr.z) * hp + acc2 * hs;
            acc3 = __builtin_bit_cast(h2, vr.w) * hp + acc3 * hs;
            m = mn;
        }
        int rem = cnt & 3;
        if (rem) {
            bool val = qb < rem;
            int s = __shfl(sl, full * 4 + qb);  // masked lanes read sl=0 (safe)
            unsigned off = ((unsigned)s << 7) + fb;
            uint4 kr = *(const uint4*)(K + off);
            float sc = __builtin_amdgcn_fdot2(__builtin_bit_cast(h2, kr.x), q0,
                       __builtin_amdgcn_fdot2(__builtin_bit_cast(h2, kr.y), q1,
                       __builtin_amdgcn_fdot2(__builtin_bit_cast(h2, kr.z), q2,
                       __builtin_amdgcn_fdot2(__builtin_bit_cast(h2, kr.w), q3,
                                              0.f, false), false), false), false);
            sc += __shfl_xor(sc, 1);
            sc += __shfl_xor(sc, 2);
            sc += __shfl_xor(sc, 4);
            uint4 vr = *(const uint4*)(V + off);
            float mn = val ? fmaxf(m, sc) : m;
            float ss = __expf(m - mn);
            float p = val ? __expf(sc - mn) : 0.f;
            denom = denom * ss + p;
            h2 hp = pk2(p, p);
            h2 hs = pk2(ss, ss);
            acc0 = __builtin_bit_cast(h2, vr.x) * hp + acc0 * hs;
            acc1 = __builtin_bit_cast(h2, vr.y) * hp + acc1 * hs;
            acc2 = __builtin_bit_cast(h2, vr.z) * hp + acc2 * hs;
            acc3 = __builtin_bit_cast(h2, vr.w) * hp + acc3 * hs;
            m = mn;
        }
    }

    // merge quarter states in packed fp16: lanes L, L^16, L^32, L^48 share role
#pragma unroll
    for (int dist = 16; dist <= 32; dist <<= 1) {
        float mo = __shfl_xor(m, dist);
        float dn = __shfl_xor(denom, dist);
        unsigned w0 = __shfl_xor(__builtin_bit_cast(unsigned, acc0), dist);
        unsigned w1 = __shfl_xor(__builtin_bit_cast(unsigned, acc1), dist);
        unsigned w2 = __shfl_xor(__builtin_bit_cast(unsigned, acc2), dist);
        unsigned w3 = __shfl_xor(__builtin_bit_cast(unsigned, acc3), dist);
        float mn = fmaxf(m, mo);
        float sA = __expf(m - mn), sB = __expf(mo - mn);
        denom = denom * sA + dn * sB;
        h2 hA = pk2(sA, sA), hB = pk2(sB, sB);
        acc0 = acc0 * hA + __builtin_bit_cast(h2, w0) * hB;
        acc1 = acc1 * hA + __builtin_bit_cast(h2, w1) * hB;
        acc2 = acc2 * hA + __builtin_bit_cast(h2, w2) * hB;
        acc3 = acc3 * hA + __builtin_bit_cast(h2, w3) * hB;
        m = mn;
    }

    if (lane < 16) {
        float inv = (denom > 0.f) ? 1.f / denom : 0.f;
        float* hp = H + (((unsigned)wid << 7) + fb);
        float4 h0 = *(float4*)hp;
        float4 h1 = *(float4*)(hp + 4);
        float o0 = h0.x + (float)acc0.x * inv, o1 = h0.y + (float)acc0.y * inv;
        float o2 = h0.z + (float)acc1.x * inv, o3 = h0.w + (float)acc1.y * inv;
        float o4 = h1.x + (float)acc2.x * inv, o5 = h1.y + (float)acc2.y * inv;
        float o6 = h1.z + (float)acc3.x * inv, o7 = h1.w + (float)acc3.y * inv;
        if (act) {
            o0 = gelu_f(o0); o1 = gelu_f(o1); o2 = gelu_f(o2); o3 = gelu_f(o3);
            o4 = gelu_f(o4); o5 = gelu_f(o5); o6 = gelu_f(o6); o7 = gelu_f(o7);
        }
        float4 w0 = {o0, o1, o2, o3};
        float4 w1 = {o4, o5, o6, o7};
        *(float4*)hp = w0;
        *(float4*)(hp + 4) = w1;
    }
}

extern "C" void kernel_launch(void* const* d_in, const int* in_sizes, int n_in,
                              void* d_out, int out_size, void* d_ws, size_t ws_size,
                              hipStream_t stream) {
    const float* x     = (const float*)d_in[0];
    const int*   src   = (const int*)d_in[1];
    const int*   dst   = (const int*)d_in[2];
    const float* fc0_w = (const float*)d_in[3];
    const float* fc0_b = (const float*)d_in[4];
    const float* Wk    = (const float*)d_in[5];
    const float* bk    = (const float*)d_in[6];
    const float* Wq    = (const float*)d_in[7];
    const float* bq    = (const float*)d_in[8];
    const float* Wv    = (const float*)d_in[9];
    const float* bv    = (const float*)d_in[10];
    const float* ws_w  = (const float*)d_in[11];
    const float* ws_b  = (const float*)d_in[12];
    const float* fc1_w = (const float*)d_in[13];
    const float* fc1_b = (const float*)d_in[14];
    const float* fc2_w = (const float*)d_in[15];
    const float* fc2_b = (const float*)d_in[16];

    int n = in_sizes[0] / 16;
    int e = in_sizes[1];

    float*  hA  = (float*)d_ws;
    float*  hB  = hA + (size_t)n * 128;
    ushort* Kb  = (ushort*)(hB + (size_t)n * 128);
    ushort* Qb  = Kb + (size_t)n * 128;
    ushort* Vb  = Qb + (size_t)n * 128;
    ushort* Wp  = Vb + (size_t)n * 128;   // 9 * 16384 fp16
    int* deg    = (int*)(Wp + 9 * 16384);
    int* rowp   = deg + n;
    int* csrc   = rowp + n + 1;
    int* rank   = csrc + e;
    int* bsum   = rank + e;               // 128 ints scratch

    int nb = (n + 1023) / 1024;

    // CSR build
    k_zero<<<(n + 255) / 256, 256, 0, stream>>>(deg, n);
    k_hist<<<(e + 255) / 256, 256, 0, stream>>>(dst, deg, rank, e);
    k_part<<<nb, 256, 0, stream>>>(deg, rowp, bsum, n);
    k_scanb<<<1, 128, 0, stream>>>(bsum, nb);
    k_add<<<nb, 256, 0, stream>>>(rowp, bsum, n, e);
    k_scatter<<<(e + 255) / 256, 256, 0, stream>>>(src, dst, rank, rowp, csrc, e);

    // pack all 9 weight matrices to fp16 frag-major
    k_pack<<<dim3(64, 9), 256, 0, stream>>>(Wk, Wq, Wv, ws_w, fc1_w, Wp);

    // fc0 (fp32)
    k_fc0<<<(n + 1) / 2, 256, 0, stream>>>(x, fc0_w, fc0_b, hA, n);

    int gx = (n + 63) / 64;
    // layer 0: k,q,v -> fp16; ws -> fp32 into hB. Then edge (+gelu).
    k_gemm_mfma<<<gx, 256, 0, stream>>>(hA, n, Wp, bk, Kb, bq, Qb, bv, Vb, ws_b, hB,
                                        nullptr, nullptr, nullptr, 0x07, 4);
    k_edge_hf<<<(n + 3) / 4, 256, 0, stream>>>(Kb, Qb, Vb, rowp, csrc, hB, n, 1);
    // layer 1
    k_gemm_mfma<<<gx, 256, 0, stream>>>(hB, n, Wp + 4 * 16384, bk + 128, Kb, bq + 128,
                                        Qb, bv + 128, Vb, ws_b + 128, hA,
                                        nullptr, nullptr, nullptr, 0x07, 4);
    k_edge_hf<<<(n + 3) / 4, 256, 0, stream>>>(Kb, Qb, Vb, rowp, csrc, hA, n, 0);

    // fc1 + gelu + fc2 fused -> d_out
    k_gemm_mfma<<<gx, 256, 0, stream>>>(hA, n, Wp + 8 * 16384, fc1_b, nullptr,
                                        fc1_b, nullptr, fc1_b, nullptr, fc1_b,
                                        nullptr, fc2_w, fc2_b, (float*)d_out,
                                        0x10000, 1);
}

// Round 11
// 683.396 us; speedup vs baseline: 1.0113x; 1.0113x over previous
//
#include <hip/hip_runtime.h>
#include <math.h>

// GAT forward. R11 = R10 with the W-prefetch stride fix: one packed matrix is
// 2048 uint4 (16384 ushorts), prefetch indexed (m+1)*1024 -> read W_{m+1}
// from the middle of W_m (absmax 6.9). Now (m+1)*2048.
// R10 structure: W staged per-matrix into LDS (frag-major, linear
// ds_read_b128), register-prefetch of next matrix's W overlapping current
// matrix's MFMAs; fc1+gelu+fc2 fused in its own kernel.

typedef _Float16 f16x8 __attribute__((ext_vector_type(8)));
typedef _Float16 h2 __attribute__((ext_vector_type(2)));
typedef float f32x4 __attribute__((ext_vector_type(4)));

__device__ __forceinline__ ushort f2h(float x) {
    union { _Float16 h; ushort u; } v;
    v.h = (_Float16)x;
    return v.u;
}
__device__ __forceinline__ float h2f(ushort u) {
    union { ushort u; _Float16 h; } v;
    v.u = u;
    return (float)v.h;
}

// gelu tanh-approx; tanh(y) via e^{2y}: gelu = x * t / (t + 1), t = exp(2y)
__device__ __forceinline__ float gelu_f(float x) {
    float y = 0.7978845608028654f * (x + 0.044715f * x * x * x);
    float t = __expf(2.f * y);
    return x * t / (t + 1.f);
}

__device__ __forceinline__ h2 pk2(float a, float b) {
    return __builtin_bit_cast(h2, __builtin_amdgcn_cvt_pkrtz(a, b));
}

// ---------------- CSR build ----------------
__global__ void k_zero(int* __restrict__ p, int n) {
    int i = blockIdx.x * blockDim.x + threadIdx.x;
    if (i < n) p[i] = 0;
}

__global__ void k_hist(const int* __restrict__ dst, int* __restrict__ deg,
                       int* __restrict__ rank, int e) {
    int i = blockIdx.x * blockDim.x + threadIdx.x;
    if (i < e) rank[i] = atomicAdd(&deg[dst[i]], 1);
}

__global__ __launch_bounds__(256) void k_part(const int* __restrict__ deg,
                                              int* __restrict__ pre,
                                              int* __restrict__ bsum, int n) {
    __shared__ int lds[256];
    int t = threadIdx.x;
    int base = blockIdx.x * 1024 + t * 4;
    int d0 = 0, d1 = 0, d2 = 0, d3 = 0;
    if (base + 3 < n) {
        int4 d = *(const int4*)&deg[base];
        d0 = d.x; d1 = d.y; d2 = d.z; d3 = d.w;
    } else {
        if (base + 0 < n) d0 = deg[base + 0];
        if (base + 1 < n) d1 = deg[base + 1];
        if (base + 2 < n) d2 = deg[base + 2];
        if (base + 3 < n) d3 = deg[base + 3];
    }
    int s0 = d0, s1 = s0 + d1, s2 = s1 + d2, s3 = s2 + d3;
    lds[t] = s3;
    __syncthreads();
    for (int off = 1; off < 256; off <<= 1) {
        int v = (t >= off) ? lds[t - off] : 0;
        __syncthreads();
        lds[t] += v;
        __syncthreads();
    }
    int excl = lds[t] - s3;
    if (base + 0 < n) pre[base + 0] = excl;
    if (base + 1 < n) pre[base + 1] = excl + s0;
    if (base + 2 < n) pre[base + 2] = excl + s1;
    if (base + 3 < n) pre[base + 3] = excl + s2;
    if (t == 255) bsum[blockIdx.x] = lds[255];
}

__global__ void k_scanb(int* __restrict__ bsum, int nb) {
    __shared__ int lds[128];
    int t = threadIdx.x;
    int v = (t < nb) ? bsum[t] : 0;
    lds[t] = v;
    __syncthreads();
    for (int off = 1; off < 128; off <<= 1) {
        int u = (t >= off) ? lds[t - off] : 0;
        __syncthreads();
        lds[t] += u;
        __syncthreads();
    }
    if (t < nb) bsum[t] = lds[t] - v;
}

__global__ __launch_bounds__(256) void k_add(int* __restrict__ rowp,
                                             const int* __restrict__ bsum, int n,
                                             int e) {
    int t = threadIdx.x;
    int base = blockIdx.x * 1024 + t * 4;
    int off = bsum[blockIdx.x];
#pragma unroll
    for (int j = 0; j < 4; ++j) {
        int i = base + j;
        if (i < n) rowp[i] += off;
    }
    if (blockIdx.x == 0 && t == 0) rowp[n] = e;
}

__global__ void k_scatter(const int* __restrict__ src, const int* __restrict__ dst,
                          const int* __restrict__ rank, const int* __restrict__ rowp,
                          int* __restrict__ csrc, int e) {
    int i = blockIdx.x * blockDim.x + threadIdx.x;
    if (i < e) csrc[rowp[dst[i]] + rank[i]] = src[i];
}

// ---------------- W pack: fp32 [128][128] -> fp16 frag-major ----------------
__global__ void k_pack(const float* __restrict__ Wk, const float* __restrict__ Wq,
                       const float* __restrict__ Wv, const float* __restrict__ Ws,
                       const float* __restrict__ Wfc1, ushort* __restrict__ Wp) {
    int id = blockIdx.y;
    const float* src;
    if (id < 8) {
        int m = id & 3, layer = id >> 2;
        src = (m == 0) ? Wk : (m == 1) ? Wq : (m == 2) ? Wv : Ws;
        src += layer * 16384;
    } else {
        src = Wfc1;
    }
    int o = blockIdx.x * 256 + threadIdx.x;
    int j = o & 7, l = (o >> 3) & 63, nf = (o >> 9) & 7, kc = o >> 12;
    int row = kc * 32 + ((l >> 4) << 3) + j;
    int col = nf * 16 + (l & 15);
    Wp[id * 16384 + o] = f2h(src[row * 128 + col]);
}

// ---------------- fc0: [N,16] @ [16,128] + b (fp32) ----------------
__global__ __launch_bounds__(256) void k_fc0(const float* __restrict__ X,
                                             const float* __restrict__ W,
                                             const float* __restrict__ b,
                                             float* __restrict__ H, int n) {
    __shared__ float Ws[16 * 128];
    __shared__ float xs[2][16];
    int t = threadIdx.x;
#pragma unroll
    for (int i = 0; i < 8; ++i) Ws[t + i * 256] = W[t + i * 256];
    if (t < 32) {
        int nn = blockIdx.x * 2 + (t >> 4);
        xs[t >> 4][t & 15] = (nn < n) ? X[nn * 16 + (t & 15)] : 0.f;
    }
    __syncthreads();
    int nd = blockIdx.x * 2 + (t >> 7);
    if (nd < n) {
        int c = t & 127;
        float acc = b[c];
#pragma unroll
        for (int j = 0; j < 16; ++j) acc += xs[t >> 7][j] * Ws[j * 128 + c];
        H[nd * 128 + c] = acc;
    }
}

// ---- common A staging: fp32 global -> fp16 LDS [64][128], XOR-swizzled ----
__device__ __forceinline__ void stage_A(const float* __restrict__ A, int n,
                                        int rbase, char* Asb, int t) {
#pragma unroll
    for (int i = 0; i < 8; ++i) {
        int f = t * 4 + i * 1024;
        int r = f >> 7, c = f & 127;
        float4 v = {0.f, 0.f, 0.f, 0.f};
        if (rbase + r < n) v = *(const float4*)&A[(size_t)(rbase + r) * 128 + c];
        ushort4 u;
        u.x = f2h(v.x); u.y = f2h(v.y); u.z = f2h(v.z); u.w = f2h(v.w);
        int byte = (r * 256 + c * 2) ^ ((r & 7) << 4);
        *(ushort4*)(Asb + byte) = u;
    }
}

// ---------------- proj GEMM: [N,128] @ [128,128] x 4 ----------------
__global__ __launch_bounds__(256) void k_gemm_proj(
    const float* __restrict__ A, int n, const ushort* __restrict__ Wp,
    const float* __restrict__ b0, void* __restrict__ o0,
    const float* __restrict__ b1, void* __restrict__ o1,
    const float* __restrict__ b2_, void* __restrict__ o2,
    const float* __restrict__ b3, void* __restrict__ o3,
    int flags) {
    __shared__ ushort As[64 * 128];   // 16 KB
    __shared__ ushort Ws[16384];      // 32 KB (one matrix, frag-major)
    char* Asb = (char*)As;
    int t = threadIdx.x;
    int rbase = blockIdx.x * 64;

    stage_A(A, n, rbase, Asb, t);

    // prefetch W_0 into registers (linear copy; one matrix = 2048 uint4)
    const uint4* wsrc = (const uint4*)Wp;
    uint4 wreg[8];
#pragma unroll
    for (int i = 0; i < 8; ++i) wreg[i] = wsrc[t + i * 256];

    __syncthreads();  // As ready

    int w = t >> 6, l = t & 63;
    int arow = w * 16 + (l & 15);
    int kq = l >> 4;

    f16x8 a[4];
#pragma unroll
    for (int kc = 0; kc < 4; ++kc) {
        int byte = (arow * 256 + kc * 64 + kq * 16) ^ ((arow & 7) << 4);
        a[kc] = *(const f16x8*)(Asb + byte);
    }

    for (int m = 0; m < 4; ++m) {
        // write prefetched W_m regs -> LDS
#pragma unroll
        for (int i = 0; i < 8; ++i) ((uint4*)Ws)[t + i * 256] = wreg[i];
        __syncthreads();  // Ws ready

        // issue next matrix's prefetch (stride 2048 uint4 per matrix);
        // return overlaps with MFMAs below
        if (m < 3) {
#pragma unroll
            for (int i = 0; i < 8; ++i)
                wreg[i] = wsrc[(m + 1) * 2048 + t + i * 256];
        }

        const float* bias; void* op;
        if (m == 0)      { bias = b0; op = o0; }
        else if (m == 1) { bias = b1; op = o1; }
        else if (m == 2) { bias = b2_; op = o2; }
        else             { bias = b3; op = o3; }
        int isf16 = (flags >> m) & 1;
        int act   = (flags >> (8 + m)) & 1;

        f32x4 acc[8];
#pragma unroll
        for (int nf = 0; nf < 8; ++nf) acc[nf] = (f32x4){0.f, 0.f, 0.f, 0.f};

#pragma unroll
        for (int kc = 0; kc < 4; ++kc) {
#pragma unroll
            for (int nf = 0; nf < 8; ++nf) {
                f16x8 b = *(const f16x8*)(Ws + (((kc * 8 + nf) * 64 + l) << 3));
                acc[nf] = __builtin_amdgcn_mfma_f32_16x16x32_f16(a[kc], b, acc[nf], 0, 0, 0);
            }
        }

#pragma unroll
        for (int nf = 0; nf < 8; ++nf) {
            int col = nf * 16 + (l & 15);
            float bia = bias[col];
#pragma unroll
            for (int r = 0; r < 4; ++r) {
                int row = rbase + w * 16 + (l >> 4) * 4 + r;
                if (row < n) {
                    float o = acc[nf][r] + bia;
                    if (act) o = gelu_f(o);
                    if (isf16) ((ushort*)op)[(size_t)row * 128 + col] = f2h(o);
                    else       ((float*)op)[(size_t)row * 128 + col] = o;
                }
            }
        }
        __syncthreads();  // all waves done reading Ws before overwrite
    }
}

// ---------------- fc GEMM: fc1 (gelu) + fc2 fused -> out [N,4] ----------------
__global__ __launch_bounds__(256) void k_gemm_fc(
    const float* __restrict__ A, int n, const ushort* __restrict__ Wp,
    const float* __restrict__ bias1, const float* __restrict__ W2,
    const float* __restrict__ bias2, float* __restrict__ out2) {
    __shared__ ushort As[64 * 128];
    __shared__ ushort Ws[16384];
    char* Asb = (char*)As;
    int t = threadIdx.x;
    int rbase = blockIdx.x * 64;

    stage_A(A, n, rbase, Asb, t);

    const uint4* wsrc = (const uint4*)Wp;
#pragma unroll
    for (int i = 0; i < 8; ++i) ((uint4*)Ws)[t + i * 256] = wsrc[t + i * 256];

    __syncthreads();

    int w = t >> 6, l = t & 63;
    int arow = w * 16 + (l & 15);
    int kq = l >> 4;

    f16x8 a[4];
#pragma unroll
    for (int kc = 0; kc < 4; ++kc) {
        int byte = (arow * 256 + kc * 64 + kq * 16) ^ ((arow & 7) << 4);
        a[kc] = *(const f16x8*)(Asb + byte);
    }

    f32x4 acc[8];
#pragma unroll
    for (int nf = 0; nf < 8; ++nf) acc[nf] = (f32x4){0.f, 0.f, 0.f, 0.f};

#pragma unroll
    for (int kc = 0; kc < 4; ++kc) {
#pragma unroll
        for (int nf = 0; nf < 8; ++nf) {
            f16x8 b = *(const f16x8*)(Ws + (((kc * 8 + nf) * 64 + l) << 3));
            acc[nf] = __builtin_amdgcn_mfma_f32_16x16x32_f16(a[kc], b, acc[nf], 0, 0, 0);
        }
    }

    // fc1 gelu + fc2 [128x4] fused epilogue: per-lane partials, 16-lane reduce
    float pj[4][4];
#pragma unroll
    for (int r = 0; r < 4; ++r)
#pragma unroll
        for (int j = 0; j < 4; ++j) pj[r][j] = 0.f;
#pragma unroll
    for (int nf = 0; nf < 8; ++nf) {
        int col = nf * 16 + (l & 15);
        float4 w2v = *(const float4*)&W2[col * 4];
        float bia = bias1[col];
#pragma unroll
        for (int r = 0; r < 4; ++r) {
            float o = gelu_f(acc[nf][r] + bia);
            pj[r][0] += o * w2v.x;
            pj[r][1] += o * w2v.y;
            pj[r][2] += o * w2v.z;
            pj[r][3] += o * w2v.w;
        }
    }
#pragma unroll
    for (int off = 1; off < 16; off <<= 1)
#pragma unroll
        for (int r = 0; r < 4; ++r)
#pragma unroll
            for (int j = 0; j < 4; ++j)
                pj[r][j] += __shfl_xor(pj[r][j], off);
    int jj = l & 15;
    if (jj < 4) {
#pragma unroll
        for (int r = 0; r < 4; ++r) {
            int row = rbase + w * 16 + (l >> 4) * 4 + r;
            if (row < n) {
                float v = (jj == 0) ? pj[r][0] : (jj == 1) ? pj[r][1]
                        : (jj == 2) ? pj[r][2] : pj[r][3];
                out2[(size_t)row * 4 + jj] = v + bias2[jj];
            }
        }
    }
}

// ---------------- fused edge phase: one wave/dst node, 4 edges/iter --------
__global__ void k_edge_hf(const ushort* __restrict__ K, const ushort* __restrict__ Q,
                          const ushort* __restrict__ V, const int* __restrict__ rowp,
                          const int* __restrict__ csrc, float* __restrict__ H, int n,
                          int act) {
    int wid = (int)((blockIdx.x * blockDim.x + threadIdx.x) >> 6);
    int lane = threadIdx.x & 63;
    if (wid >= n) return;
    int qb = lane >> 4;                 // edge slot within quad
    unsigned fb = (lane & 15) * 8u;     // feature base
    int e0 = rowp[wid], e1 = rowp[wid + 1];

    uint4 qr = *(const uint4*)(Q + (((unsigned)wid << 7) + fb));
    h2 q0 = __builtin_bit_cast(h2, qr.x), q1 = __builtin_bit_cast(h2, qr.y);
    h2 q2 = __builtin_bit_cast(h2, qr.z), q3 = __builtin_bit_cast(h2, qr.w);

    float m = -1e30f, denom = 0.f;
    h2 hz = {(_Float16)0.f, (_Float16)0.f};
    h2 acc0 = hz, acc1 = hz, acc2 = hz, acc3 = hz;

    for (int eb = e0; eb < e1; eb += 64) {
        int cnt = min(64, e1 - eb);
        int sl = (eb + lane < e1) ? csrc[eb + lane] : 0;
        int full = cnt >> 2;
#pragma unroll 2
        for (int j = 0; j < full; ++j) {
            int s = __shfl(sl, 4 * j + qb);
            unsigned off = ((unsigned)s << 7) + fb;
            uint4 kr = *(const uint4*)(K + off);
            float sc = __builtin_amdgcn_fdot2(__builtin_bit_cast(h2, kr.x), q0,
                       __builtin_amdgcn_fdot2(__builtin_bit_cast(h2, kr.y), q1,
                       __builtin_amdgcn_fdot2(__builtin_bit_cast(h2, kr.z), q2,
                       __builtin_amdgcn_fdot2(__builtin_bit_cast(h2, kr.w), q3,
                                              0.f, false), false), false), false);
            sc += __shfl_xor(sc, 1);
            sc += __shfl_xor(sc, 2);
            sc += __shfl_xor(sc, 4);
            uint4 vr = *(const uint4*)(V + off);
            float mn = fmaxf(m, sc);
            float ss = __expf(m - mn);
            float p = __expf(sc - mn);
            denom = denom * ss + p;
            h2 hp = pk2(p, p);
            h2 hs = pk2(ss, ss);
            acc0 = __builtin_bit_cast(h2, vr.x) * hp + acc0 * hs;
            acc1 = __builtin_bit_cast(h2, vr.y) * hp + acc1 * hs;
            acc2 = __builtin_bit_cast(h2, vr.z) * hp + acc2 * hs;
            acc3 = __builtin_bit_cast(h2, vr.w) * hp + acc3 * hs;
            m = mn;
        }
        int rem = cnt & 3;
        if (rem) {
            bool val = qb < rem;
            int s = __shfl(sl, full * 4 + qb);
            unsigned off = ((unsigned)s << 7) + fb;
            uint4 kr = *(const uint4*)(K + off);
            float sc = __builtin_amdgcn_fdot2(__builtin_bit_cast(h2, kr.x), q0,
                       __builtin_amdgcn_fdot2(__builtin_bit_cast(h2, kr.y), q1,
                       __builtin_amdgcn_fdot2(__builtin_bit_cast(h2, kr.z), q2,
                       __builtin_amdgcn_fdot2(__builtin_bit_cast(h2, kr.w), q3,
                                              0.f, false), false), false), false);
            sc += __shfl_xor(sc, 1);
            sc += __shfl_xor(sc, 2);
            sc += __shfl_xor(sc, 4);
            uint4 vr = *(const uint4*)(V + off);
            float mn = val ? fmaxf(m, sc) : m;
            float ss = __expf(m - mn);
            float p = val ? __expf(sc - mn) : 0.f;
            denom = denom * ss + p;
            h2 hp = pk2(p, p);
            h2 hs = pk2(ss, ss);
            acc0 = __builtin_bit_cast(h2, vr.x) * hp + acc0 * hs;
            acc1 = __builtin_bit_cast(h2, vr.y) * hp + acc1 * hs;
            acc2 = __builtin_bit_cast(h2, vr.z) * hp + acc2 * hs;
            acc3 = __builtin_bit_cast(h2, vr.w) * hp + acc3 * hs;
            m = mn;
        }
    }

#pragma unroll
    for (int dist = 16; dist <= 32; dist <<= 1) {
        float mo = __shfl_xor(m, dist);
        float dn = __shfl_xor(denom, dist);
        unsigned w0 = __shfl_xor(__builtin_bit_cast(unsigned, acc0), dist);
        unsigned w1 = __shfl_xor(__builtin_bit_cast(unsigned, acc1), dist);
        unsigned w2 = __shfl_xor(__builtin_bit_cast(unsigned, acc2), dist);
        unsigned w3 = __shfl_xor(__builtin_bit_cast(unsigned, acc3), dist);
        float mn = fmaxf(m, mo);
        float sA = __expf(m - mn), sB = __expf(mo - mn);
        denom = denom * sA + dn * sB;
        h2 hA = pk2(sA, sA), hB = pk2(sB, sB);
        acc0 = acc0 * hA + __builtin_bit_cast(h2, w0) * hB;
        acc1 = acc1 * hA + __builtin_bit_cast(h2, w1) * hB;
        acc2 = acc2 * hA + __builtin_bit_cast(h2, w2) * hB;
        acc3 = acc3 * hA + __builtin_bit_cast(h2, w3) * hB;
        m = mn;
    }

    if (lane < 16) {
        float inv = (denom > 0.f) ? 1.f / denom : 0.f;
        float* hp = H + (((unsigned)wid << 7) + fb);
        float4 h0 = *(float4*)hp;
        float4 h1 = *(float4*)(hp + 4);
        float o0 = h0.x + (float)acc0.x * inv, o1 = h0.y + (float)acc0.y * inv;
        float o2 = h0.z + (float)acc1.x * inv, o3 = h0.w + (float)acc1.y * inv;
        float o4 = h1.x + (float)acc2.x * inv, o5 = h1.y + (float)acc2.y * inv;
        float o6 = h1.z + (float)acc3.x * inv, o7 = h1.w + (float)acc3.y * inv;
        if (act) {
            o0 = gelu_f(o0); o1 = gelu_f(o1); o2 = gelu_f(o2); o3 = gelu_f(o3);
            o4 = gelu_f(o4); o5 = gelu_f(o5); o6 = gelu_f(o6); o7 = gelu_f(o7);
        }
        float4 w0 = {o0, o1, o2, o3};
        float4 w1 = {o4, o5, o6, o7};
        *(float4*)hp = w0;
        *(float4*)(hp + 4) = w1;
    }
}

extern "C" void kernel_launch(void* const* d_in, const int* in_sizes, int n_in,
                              void* d_out, int out_size, void* d_ws, size_t ws_size,
                              hipStream_t stream) {
    const float* x     = (const float*)d_in[0];
    const int*   src   = (const int*)d_in[1];
    const int*   dst   = (const int*)d_in[2];
    const float* fc0_w = (const float*)d_in[3];
    const float* fc0_b = (const float*)d_in[4];
    const float* Wk    = (const float*)d_in[5];
    const float* bk    = (const float*)d_in[6];
    const float* Wq    = (const float*)d_in[7];
    const float* bq    = (const float*)d_in[8];
    const float* Wv    = (const float*)d_in[9];
    const float* bv    = (const float*)d_in[10];
    const float* ws_w  = (const float*)d_in[11];
    const float* ws_b  = (const float*)d_in[12];
    const float* fc1_w = (const float*)d_in[13];
    const float* fc1_b = (const float*)d_in[14];
    const float* fc2_w = (const float*)d_in[15];
    const float* fc2_b = (const float*)d_in[16];

    int n = in_sizes[0] / 16;
    int e = in_sizes[1];

    float*  hA  = (float*)d_ws;
    float*  hB  = hA + (size_t)n * 128;
    ushort* Kb  = (ushort*)(hB + (size_t)n * 128);
    ushort* Qb  = Kb + (size_t)n * 128;
    ushort* Vb  = Qb + (size_t)n * 128;
    ushort* Wp  = Vb + (size_t)n * 128;   // 9 * 16384 fp16
    int* deg    = (int*)(Wp + 9 * 16384);
    int* rowp   = deg + n;
    int* csrc   = rowp + n + 1;
    int* rank   = csrc + e;
    int* bsum   = rank + e;               // 128 ints scratch

    int nb = (n + 1023) / 1024;

    // CSR build
    k_zero<<<(n + 255) / 256, 256, 0, stream>>>(deg, n);
    k_hist<<<(e + 255) / 256, 256, 0, stream>>>(dst, deg, rank, e);
    k_part<<<nb, 256, 0, stream>>>(deg, rowp, bsum, n);
    k_scanb<<<1, 128, 0, stream>>>(bsum, nb);
    k_add<<<nb, 256, 0, stream>>>(rowp, bsum, n, e);
    k_scatter<<<(e + 255) / 256, 256, 0, stream>>>(src, dst, rank, rowp, csrc, e);

    // pack all 9 weight matrices to fp16 frag-major
    k_pack<<<dim3(64, 9), 256, 0, stream>>>(Wk, Wq, Wv, ws_w, fc1_w, Wp);

    // fc0 (fp32)
    k_fc0<<<(n + 1) / 2, 256, 0, stream>>>(x, fc0_w, fc0_b, hA, n);

    int gx = (n + 63) / 64;
    // layer 0: k,q,v -> fp16; ws -> fp32 into hB. Then edge (+gelu).
    k_gemm_proj<<<gx, 256, 0, stream>>>(hA, n, Wp, bk, Kb, bq, Qb, bv, Vb, ws_b,
                                        hB, 0x07);
    k_edge_hf<<<(n + 3) / 4, 256, 0, stream>>>(Kb, Qb, Vb, rowp, csrc, hB, n, 1);
    // layer 1
    k_gemm_proj<<<gx, 256, 0, stream>>>(hB, n, Wp + 4 * 16384, bk + 128, Kb,
                                        bq + 128, Qb, bv + 128, Vb, ws_b + 128,
                                        hA, 0x07);
    k_edge_hf<<<(n + 3) / 4, 256, 0, stream>>>(Kb, Qb, Vb, rowp, csrc, hA, n, 0);

    // fc1 + gelu + fc2 fused -> d_out
    k_gemm_fc<<<gx, 256, 0, stream>>>(hA, n, Wp + 8 * 16384, fc1_b, fc2_w, fc2_b,
                                      (float*)d_out);
}

// Round 12
// 544.665 us; speedup vs baseline: 1.2689x; 1.2547x over previous
//
#include <hip/hip_runtime.h>
#include <math.h>

// GAT forward. R12: coalesced GEMM epilogue + fp16 residual stream.
// R11 profile: k_gemm_proj 137us with 417MB/dispatch (303MB WRITE vs 128MB
// ideal) — scattered 32B epilogue stores caused write-allocate RMW
// amplification. Now: C bounced through LDS (swizzled) -> full-wave 1KB
// streaming stores; h stored fp16 (hA/hB), halving A reads + edge H traffic.
// Structure: CSR build -> W pack -> fc0(fp16 out) -> 2x [ gemm_proj(4x fp16)
// -> fused edge (fp16 H) ] -> gemm_fc (fc1+gelu+fc2 fused).

typedef _Float16 f16x8 __attribute__((ext_vector_type(8)));
typedef _Float16 h2 __attribute__((ext_vector_type(2)));
typedef float f32x4 __attribute__((ext_vector_type(4)));

__device__ __forceinline__ ushort f2h(float x) {
    union { _Float16 h; ushort u; } v;
    v.h = (_Float16)x;
    return v.u;
}
__device__ __forceinline__ float h2f(ushort u) {
    union { ushort u; _Float16 h; } v;
    v.u = u;
    return (float)v.h;
}

// gelu tanh-approx; tanh via e^{2y}: gelu = x * t / (t + 1), t = exp(2y)
__device__ __forceinline__ float gelu_f(float x) {
    float y = 0.7978845608028654f * (x + 0.044715f * x * x * x);
    float t = __expf(2.f * y);
    return x * t / (t + 1.f);
}

__device__ __forceinline__ h2 pk2(float a, float b) {
    return __builtin_bit_cast(h2, __builtin_amdgcn_cvt_pkrtz(a, b));
}

// ---------------- CSR build ----------------
__global__ void k_zero(int* __restrict__ p, int n) {
    int i = blockIdx.x * blockDim.x + threadIdx.x;
    if (i < n) p[i] = 0;
}

__global__ void k_hist(const int* __restrict__ dst, int* __restrict__ deg,
                       int* __restrict__ rank, int e) {
    int i = blockIdx.x * blockDim.x + threadIdx.x;
    if (i < e) rank[i] = atomicAdd(&deg[dst[i]], 1);
}

__global__ __launch_bounds__(256) void k_part(const int* __restrict__ deg,
                                              int* __restrict__ pre,
                                              int* __restrict__ bsum, int n) {
    __shared__ int lds[256];
    int t = threadIdx.x;
    int base = blockIdx.x * 1024 + t * 4;
    int d0 = 0, d1 = 0, d2 = 0, d3 = 0;
    if (base + 3 < n) {
        int4 d = *(const int4*)&deg[base];
        d0 = d.x; d1 = d.y; d2 = d.z; d3 = d.w;
    } else {
        if (base + 0 < n) d0 = deg[base + 0];
        if (base + 1 < n) d1 = deg[base + 1];
        if (base + 2 < n) d2 = deg[base + 2];
        if (base + 3 < n) d3 = deg[base + 3];
    }
    int s0 = d0, s1 = s0 + d1, s2 = s1 + d2, s3 = s2 + d3;
    lds[t] = s3;
    __syncthreads();
    for (int off = 1; off < 256; off <<= 1) {
        int v = (t >= off) ? lds[t - off] : 0;
        __syncthreads();
        lds[t] += v;
        __syncthreads();
    }
    int excl = lds[t] - s3;
    if (base + 0 < n) pre[base + 0] = excl;
    if (base + 1 < n) pre[base + 1] = excl + s0;
    if (base + 2 < n) pre[base + 2] = excl + s1;
    if (base + 3 < n) pre[base + 3] = excl + s2;
    if (t == 255) bsum[blockIdx.x] = lds[255];
}

__global__ void k_scanb(int* __restrict__ bsum, int nb) {
    __shared__ int lds[128];
    int t = threadIdx.x;
    int v = (t < nb) ? bsum[t] : 0;
    lds[t] = v;
    __syncthreads();
    for (int off = 1; off < 128; off <<= 1) {
        int u = (t >= off) ? lds[t - off] : 0;
        __syncthreads();
        lds[t] += u;
        __syncthreads();
    }
    if (t < nb) bsum[t] = lds[t] - v;
}

__global__ __launch_bounds__(256) void k_add(int* __restrict__ rowp,
                                             const int* __restrict__ bsum, int n,
                                             int e) {
    int t = threadIdx.x;
    int base = blockIdx.x * 1024 + t * 4;
    int off = bsum[blockIdx.x];
#pragma unroll
    for (int j = 0; j < 4; ++j) {
        int i = base + j;
        if (i < n) rowp[i] += off;
    }
    if (blockIdx.x == 0 && t == 0) rowp[n] = e;
}

__global__ void k_scatter(const int* __restrict__ src, const int* __restrict__ dst,
                          const int* __restrict__ rank, const int* __restrict__ rowp,
                          int* __restrict__ csrc, int e) {
    int i = blockIdx.x * blockDim.x + threadIdx.x;
    if (i < e) csrc[rowp[dst[i]] + rank[i]] = src[i];
}

// ---------------- W pack: fp32 [128][128] -> fp16 frag-major ----------------
__global__ void k_pack(const float* __restrict__ Wk, const float* __restrict__ Wq,
                       const float* __restrict__ Wv, const float* __restrict__ Ws,
                       const float* __restrict__ Wfc1, ushort* __restrict__ Wp) {
    int id = blockIdx.y;
    const float* src;
    if (id < 8) {
        int m = id & 3, layer = id >> 2;
        src = (m == 0) ? Wk : (m == 1) ? Wq : (m == 2) ? Wv : Ws;
        src += layer * 16384;
    } else {
        src = Wfc1;
    }
    int o = blockIdx.x * 256 + threadIdx.x;
    int j = o & 7, l = (o >> 3) & 63, nf = (o >> 9) & 7, kc = o >> 12;
    int row = kc * 32 + ((l >> 4) << 3) + j;
    int col = nf * 16 + (l & 15);
    Wp[id * 16384 + o] = f2h(src[row * 128 + col]);
}

// ---------------- fc0: [N,16] @ [16,128] + b -> fp16 ----------------
__global__ __launch_bounds__(256) void k_fc0(const float* __restrict__ X,
                                             const float* __restrict__ W,
                                             const float* __restrict__ b,
                                             ushort* __restrict__ H, int n) {
    __shared__ float Ws[16 * 128];
    __shared__ float xs[2][16];
    int t = threadIdx.x;
#pragma unroll
    for (int i = 0; i < 8; ++i) Ws[t + i * 256] = W[t + i * 256];
    if (t < 32) {
        int nn = blockIdx.x * 2 + (t >> 4);
        xs[t >> 4][t & 15] = (nn < n) ? X[nn * 16 + (t & 15)] : 0.f;
    }
    __syncthreads();
    int nd = blockIdx.x * 2 + (t >> 7);
    if (nd < n) {
        int c = t & 127;
        float acc = b[c];
#pragma unroll
        for (int j = 0; j < 16; ++j) acc += xs[t >> 7][j] * Ws[j * 128 + c];
        H[(size_t)nd * 128 + c] = f2h(acc);
    }
}

// ---- A staging: fp16 global -> fp16 LDS [64][128], XOR-swizzled ----
__device__ __forceinline__ void stage_Ah(const ushort* __restrict__ A, int n,
                                         int rbase, char* Asb, int t) {
#pragma unroll
    for (int i = 0; i < 4; ++i) {
        int b = t * 16 + i * 4096;  // byte offset in tile (row-major, 256B rows)
        int r = b >> 8;
        uint4 v = {0u, 0u, 0u, 0u};
        if (rbase + r < n)
            v = *(const uint4*)((const char*)A + (size_t)rbase * 256 + b);
        *(uint4*)(Asb + (b ^ ((r & 7) << 4))) = v;
    }
}

// ---------------- proj GEMM: [N,128] @ [128,128] x 4, all fp16 out ----------
// W_m staged into LDS (frag-major); W_{m+1} register-prefetched under MFMAs.
// Epilogue: C -> As (swizzled fp16) -> full-wave 1KB streaming stores.
__global__ __launch_bounds__(256) void k_gemm_proj(
    const ushort* __restrict__ A, int n, const ushort* __restrict__ Wp,
    const float* __restrict__ b0, ushort* __restrict__ o0,
    const float* __restrict__ b1, ushort* __restrict__ o1,
    const float* __restrict__ b2_, ushort* __restrict__ o2,
    const float* __restrict__ b3, ushort* __restrict__ o3) {
    __shared__ ushort As[64 * 128];   // 16 KB: A tile, then C staging
    __shared__ ushort Ws[16384];      // 32 KB: one W matrix
    char* Asb = (char*)As;
    int t = threadIdx.x;
    int rbase = blockIdx.x * 64;

    stage_Ah(A, n, rbase, Asb, t);

    // prefetch W_0 (one matrix = 2048 uint4)
    const uint4* wsrc = (const uint4*)Wp;
    uint4 wreg[8];
#pragma unroll
    for (int i = 0; i < 8; ++i) wreg[i] = wsrc[t + i * 256];

    __syncthreads();  // As ready

    int w = t >> 6, l = t & 63;
    int arow = w * 16 + (l & 15);
    int kq = l >> 4;

    f16x8 a[4];
#pragma unroll
    for (int kc = 0; kc < 4; ++kc) {
        int byte = (arow * 256 + kc * 64 + kq * 16) ^ ((arow & 7) << 4);
        a[kc] = *(const f16x8*)(Asb + byte);
    }
    __syncthreads();  // everyone has a[] before As is reused for C staging

    for (int m = 0; m < 4; ++m) {
        // write prefetched W_m -> Ws
#pragma unroll
        for (int i = 0; i < 8; ++i) ((uint4*)Ws)[t + i * 256] = wreg[i];
        __syncthreads();  // Ws ready; prev C-flush reads of As also done

        if (m < 3) {
#pragma unroll
            for (int i = 0; i < 8; ++i)
                wreg[i] = wsrc[(m + 1) * 2048 + t + i * 256];
        }

        const float* bias; ushort* op;
        if (m == 0)      { bias = b0; op = o0; }
        else if (m == 1) { bias = b1; op = o1; }
        else if (m == 2) { bias = b2_; op = o2; }
        else             { bias = b3; op = o3; }

        f32x4 acc[8];
#pragma unroll
        for (int nf = 0; nf < 8; ++nf) acc[nf] = (f32x4){0.f, 0.f, 0.f, 0.f};

#pragma unroll
        for (int kc = 0; kc < 4; ++kc) {
#pragma unroll
            for (int nf = 0; nf < 8; ++nf) {
                f16x8 b = *(const f16x8*)(Ws + (((kc * 8 + nf) * 64 + l) << 3));
                acc[nf] = __builtin_amdgcn_mfma_f32_16x16x32_f16(a[kc], b, acc[nf], 0, 0, 0);
            }
        }
        __syncthreads();  // Ws reads done (can overwrite next iter); As free

        // C -> As (swizzled fp16, +bias)
#pragma unroll
        for (int nf = 0; nf < 8; ++nf) {
            int col = nf * 16 + (l & 15);
            float bia = bias[col];
#pragma unroll
            for (int r = 0; r < 4; ++r) {
                int row = w * 16 + (l >> 4) * 4 + r;
                int b = (row * 256 + col * 2) ^ ((row & 7) << 4);
                *(ushort*)(Asb + b) = f2h(acc[nf][r] + bia);
            }
        }
        __syncthreads();  // C staged

        // coalesced flush: 4 x 16B per thread, full-wave 1KB streams
#pragma unroll
        for (int i = 0; i < 4; ++i) {
            int b = t * 16 + i * 4096;
            int r = b >> 8;
            uint4 v = *(const uint4*)(Asb + (b ^ ((r & 7) << 4)));
            if (rbase + r < n)
                *(uint4*)((char*)op + (size_t)rbase * 256 + b) = v;
        }
        // next iteration's Ws-write + sync fences these As reads
    }
}

// ---------------- fc GEMM: fc1 (gelu) + fc2 fused -> out [N,4] ----------------
__global__ __launch_bounds__(256) void k_gemm_fc(
    const ushort* __restrict__ A, int n, const ushort* __restrict__ Wp,
    const float* __restrict__ bias1, const float* __restrict__ W2,
    const float* __restrict__ bias2, float* __restrict__ out2) {
    __shared__ ushort As[64 * 128];
    __shared__ ushort Ws[16384];
    char* Asb = (char*)As;
    int t = threadIdx.x;
    int rbase = blockIdx.x * 64;

    stage_Ah(A, n, rbase, Asb, t);

    const uint4* wsrc = (const uint4*)Wp;
#pragma unroll
    for (int i = 0; i < 8; ++i) ((uint4*)Ws)[t + i * 256] = wsrc[t + i * 256];

    __syncthreads();

    int w = t >> 6, l = t & 63;
    int arow = w * 16 + (l & 15);
    int kq = l >> 4;

    f16x8 a[4];
#pragma unroll
    for (int kc = 0; kc < 4; ++kc) {
        int byte = (arow * 256 + kc * 64 + kq * 16) ^ ((arow & 7) << 4);
        a[kc] = *(const f16x8*)(Asb + byte);
    }

    f32x4 acc[8];
#pragma unroll
    for (int nf = 0; nf < 8; ++nf) acc[nf] = (f32x4){0.f, 0.f, 0.f, 0.f};

#pragma unroll
    for (int kc = 0; kc < 4; ++kc) {
#pragma unroll
        for (int nf = 0; nf < 8; ++nf) {
            f16x8 b = *(const f16x8*)(Ws + (((kc * 8 + nf) * 64 + l) << 3));
            acc[nf] = __builtin_amdgcn_mfma_f32_16x16x32_f16(a[kc], b, acc[nf], 0, 0, 0);
        }
    }

    // fc1 gelu + fc2 [128x4] fused epilogue
    float pj[4][4];
#pragma unroll
    for (int r = 0; r < 4; ++r)
#pragma unroll
        for (int j = 0; j < 4; ++j) pj[r][j] = 0.f;
#pragma unroll
    for (int nf = 0; nf < 8; ++nf) {
        int col = nf * 16 + (l & 15);
        float4 w2v = *(const float4*)&W2[col * 4];
        float bia = bias1[col];
#pragma unroll
        for (int r = 0; r < 4; ++r) {
            float o = gelu_f(acc[nf][r] + bia);
            pj[r][0] += o * w2v.x;
            pj[r][1] += o * w2v.y;
            pj[r][2] += o * w2v.z;
            pj[r][3] += o * w2v.w;
        }
    }
#pragma unroll
    for (int off = 1; off < 16; off <<= 1)
#pragma unroll
        for (int r = 0; r < 4; ++r)
#pragma unroll
            for (int j = 0; j < 4; ++j)
                pj[r][j] += __shfl_xor(pj[r][j], off);
    int jj = l & 15;
    if (jj < 4) {
#pragma unroll
        for (int r = 0; r < 4; ++r) {
            int row = rbase + w * 16 + (l >> 4) * 4 + r;
            if (row < n) {
                float v = (jj == 0) ? pj[r][0] : (jj == 1) ? pj[r][1]
                        : (jj == 2) ? pj[r][2] : pj[r][3];
                out2[(size_t)row * 4 + jj] = v + bias2[jj];
            }
        }
    }
}

// ---------------- fused edge phase: one wave/dst node, 4 edges/iter --------
// H is fp16 now (read-modify-write at lane<16).
__global__ void k_edge_hf(const ushort* __restrict__ K, const ushort* __restrict__ Q,
                          const ushort* __restrict__ V, const int* __restrict__ rowp,
                          const int* __restrict__ csrc, ushort* __restrict__ H, int n,
                          int act) {
    int wid = (int)((blockIdx.x * blockDim.x + threadIdx.x) >> 6);
    int lane = threadIdx.x & 63;
    if (wid >= n) return;
    int qb = lane >> 4;                 // edge slot within quad
    unsigned fb = (lane & 15) * 8u;     // feature base
    int e0 = rowp[wid], e1 = rowp[wid + 1];

    uint4 qr = *(const uint4*)(Q + (((unsigned)wid << 7) + fb));
    h2 q0 = __builtin_bit_cast(h2, qr.x), q1 = __builtin_bit_cast(h2, qr.y);
    h2 q2 = __builtin_bit_cast(h2, qr.z), q3 = __builtin_bit_cast(h2, qr.w);

    float m = -1e30f, denom = 0.f;
    h2 hz = {(_Float16)0.f, (_Float16)0.f};
    h2 acc0 = hz, acc1 = hz, acc2 = hz, acc3 = hz;

    for (int eb = e0; eb < e1; eb += 64) {
        int cnt = min(64, e1 - eb);
        int sl = (eb + lane < e1) ? csrc[eb + lane] : 0;
        int full = cnt >> 2;
#pragma unroll 2
        for (int j = 0; j < full; ++j) {
            int s = __shfl(sl, 4 * j + qb);
            unsigned off = ((unsigned)s << 7) + fb;
            uint4 kr = *(const uint4*)(K + off);
            float sc = __builtin_amdgcn_fdot2(__builtin_bit_cast(h2, kr.x), q0,
                       __builtin_amdgcn_fdot2(__builtin_bit_cast(h2, kr.y), q1,
                       __builtin_amdgcn_fdot2(__builtin_bit_cast(h2, kr.z), q2,
                       __builtin_amdgcn_fdot2(__builtin_bit_cast(h2, kr.w), q3,
                                              0.f, false), false), false), false);
            sc += __shfl_xor(sc, 1);
            sc += __shfl_xor(sc, 2);
            sc += __shfl_xor(sc, 4);
            uint4 vr = *(const uint4*)(V + off);
            float mn = fmaxf(m, sc);
            float ss = __expf(m - mn);
            float p = __expf(sc - mn);
            denom = denom * ss + p;
            h2 hp = pk2(p, p);
            h2 hs = pk2(ss, ss);
            acc0 = __builtin_bit_cast(h2, vr.x) * hp + acc0 * hs;
            acc1 = __builtin_bit_cast(h2, vr.y) * hp + acc1 * hs;
            acc2 = __builtin_bit_cast(h2, vr.z) * hp + acc2 * hs;
            acc3 = __builtin_bit_cast(h2, vr.w) * hp + acc3 * hs;
            m = mn;
        }
        int rem = cnt & 3;
        if (rem) {
            bool val = qb < rem;
            int s = __shfl(sl, full * 4 + qb);
            unsigned off = ((unsigned)s << 7) + fb;
            uint4 kr = *(const uint4*)(K + off);
            float sc = __builtin_amdgcn_fdot2(__builtin_bit_cast(h2, kr.x), q0,
                       __builtin_amdgcn_fdot2(__builtin_bit_cast(h2, kr.y), q1,
                       __builtin_amdgcn_fdot2(__builtin_bit_cast(h2, kr.z), q2,
                       __builtin_amdgcn_fdot2(__builtin_bit_cast(h2, kr.w), q3,
                                              0.f, false), false), false), false);
            sc += __shfl_xor(sc, 1);
            sc += __shfl_xor(sc, 2);
            sc += __shfl_xor(sc, 4);
            uint4 vr = *(const uint4*)(V + off);
            float mn = val ? fmaxf(m, sc) : m;
            float ss = __expf(m - mn);
            float p = val ? __expf(sc - mn) : 0.f;
            denom = denom * ss + p;
            h2 hp = pk2(p, p);
            h2 hs = pk2(ss, ss);
            acc0 = __builtin_bit_cast(h2, vr.x) * hp + acc0 * hs;
            acc1 = __builtin_bit_cast(h2, vr.y) * hp + acc1 * hs;
            acc2 = __builtin_bit_cast(h2, vr.z) * hp + acc2 * hs;
            acc3 = __builtin_bit_cast(h2, vr.w) * hp + acc3 * hs;
            m = mn;
        }
    }

#pragma unroll
    for (int dist = 16; dist <= 32; dist <<= 1) {
        float mo = __shfl_xor(m, dist);
        float dn = __shfl_xor(denom, dist);
        unsigned w0 = __shfl_xor(__builtin_bit_cast(unsigned, acc0), dist);
        unsigned w1 = __shfl_xor(__builtin_bit_cast(unsigned, acc1), dist);
        unsigned w2 = __shfl_xor(__builtin_bit_cast(unsigned, acc2), dist);
        unsigned w3 = __shfl_xor(__builtin_bit_cast(unsigned, acc3), dist);
        float mn = fmaxf(m, mo);
        float sA = __expf(m - mn), sB = __expf(mo - mn);
        denom = denom * sA + dn * sB;
        h2 hA = pk2(sA, sA), hB = pk2(sB, sB);
        acc0 = acc0 * hA + __builtin_bit_cast(h2, w0) * hB;
        acc1 = acc1 * hA + __builtin_bit_cast(h2, w1) * hB;
        acc2 = acc2 * hA + __builtin_bit_cast(h2, w2) * hB;
        acc3 = acc3 * hA + __builtin_bit_cast(h2, w3) * hB;
        m = mn;
    }

    if (lane < 16) {
        float inv = (denom > 0.f) ? 1.f / denom : 0.f;
        ushort* hp = H + (((unsigned)wid << 7) + fb);
        uint4 hr = *(const uint4*)hp;
        h2 s0 = __builtin_bit_cast(h2, hr.x), s1 = __builtin_bit_cast(h2, hr.y);
        h2 s2 = __builtin_bit_cast(h2, hr.z), s3 = __builtin_bit_cast(h2, hr.w);
        float o0 = (float)s0.x + (float)acc0.x * inv;
        float o1 = (float)s0.y + (float)acc0.y * inv;
        float o2 = (float)s1.x + (float)acc1.x * inv;
        float o3 = (float)s1.y + (float)acc1.y * inv;
        float o4 = (float)s2.x + (float)acc2.x * inv;
        float o5 = (float)s2.y + (float)acc2.y * inv;
        float o6 = (float)s3.x + (float)acc3.x * inv;
        float o7 = (float)s3.y + (float)acc3.y * inv;
        if (act) {
            o0 = gelu_f(o0); o1 = gelu_f(o1); o2 = gelu_f(o2); o3 = gelu_f(o3);
            o4 = gelu_f(o4); o5 = gelu_f(o5); o6 = gelu_f(o6); o7 = gelu_f(o7);
        }
        uint4 o;
        o.x = __builtin_bit_cast(unsigned, pk2(o0, o1));
        o.y = __builtin_bit_cast(unsigned, pk2(o2, o3));
        o.z = __builtin_bit_cast(unsigned, pk2(o4, o5));
        o.w = __builtin_bit_cast(unsigned, pk2(o6, o7));
        *(uint4*)hp = o;
    }
}

extern "C" void kernel_launch(void* const* d_in, const int* in_sizes, int n_in,
                              void* d_out, int out_size, void* d_ws, size_t ws_size,
                              hipStream_t stream) {
    const float* x     = (const float*)d_in[0];
    const int*   src   = (const int*)d_in[1];
    const int*   dst   = (const int*)d_in[2];
    const float* fc0_w = (const float*)d_in[3];
    const float* fc0_b = (const float*)d_in[4];
    const float* Wk    = (const float*)d_in[5];
    const float* bk    = (const float*)d_in[6];
    const float* Wq    = (const float*)d_in[7];
    const float* bq    = (const float*)d_in[8];
    const float* Wv    = (const float*)d_in[9];
    const float* bv    = (const float*)d_in[10];
    const float* ws_w  = (const float*)d_in[11];
    const float* ws_b  = (const float*)d_in[12];
    const float* fc1_w = (const float*)d_in[13];
    const float* fc1_b = (const float*)d_in[14];
    const float* fc2_w = (const float*)d_in[15];
    const float* fc2_b = (const float*)d_in[16];

    int n = in_sizes[0] / 16;
    int e = in_sizes[1];

    ushort* hA  = (ushort*)d_ws;
    ushort* hB  = hA + (size_t)n * 128;
    ushort* Kb  = hB + (size_t)n * 128;
    ushort* Qb  = Kb + (size_t)n * 128;
    ushort* Vb  = Qb + (size_t)n * 128;
    ushort* Wp  = Vb + (size_t)n * 128;   // 9 * 16384 fp16
    int* deg    = (int*)(Wp + 9 * 16384);
    int* rowp   = deg + n;
    int* csrc   = rowp + n + 1;
    int* rank   = csrc + e;
    int* bsum   = rank + e;               // 128 ints scratch

    int nb = (n + 1023) / 1024;

    // CSR build
    k_zero<<<(n + 255) / 256, 256, 0, stream>>>(deg, n);
    k_hist<<<(e + 255) / 256, 256, 0, stream>>>(dst, deg, rank, e);
    k_part<<<nb, 256, 0, stream>>>(deg, rowp, bsum, n);
    k_scanb<<<1, 128, 0, stream>>>(bsum, nb);
    k_add<<<nb, 256, 0, stream>>>(rowp, bsum, n, e);
    k_scatter<<<(e + 255) / 256, 256, 0, stream>>>(src, dst, rank, rowp, csrc, e);

    // pack all 9 weight matrices to fp16 frag-major
    k_pack<<<dim3(64, 9), 256, 0, stream>>>(Wk, Wq, Wv, ws_w, fc1_w, Wp);

    // fc0 -> fp16 hA
    k_fc0<<<(n + 1) / 2, 256, 0, stream>>>(x, fc0_w, fc0_b, hA, n);

    int gx = (n + 63) / 64;
    // layer 0: k,q,v,ws all fp16. Then edge (+gelu) updates hB in place.
    k_gemm_proj<<<gx, 256, 0, stream>>>(hA, n, Wp, bk, Kb, bq, Qb, bv, Vb, ws_b, hB);
    k_edge_hf<<<(n + 3) / 4, 256, 0, stream>>>(Kb, Qb, Vb, rowp, csrc, hB, n, 1);
    // layer 1
    k_gemm_proj<<<gx, 256, 0, stream>>>(hB, n, Wp + 4 * 16384, bk + 128, Kb,
                                        bq + 128, Qb, bv + 128, Vb, ws_b + 128, hA);
    k_edge_hf<<<(n + 3) / 4, 256, 0, stream>>>(Kb, Qb, Vb, rowp, csrc, hA, n, 0);

    // fc1 + gelu + fc2 fused -> d_out
    k_gemm_fc<<<gx, 256, 0, stream>>>(hA, n, Wp + 8 * 16384, fc1_b, fc2_w, fc2_b,
                                      (float*)d_out);
}